// Round 15
// baseline (251.971 us; speedup 1.0000x reference)
//
#include <hip/hip_runtime.h>
#include <math.h>

// Problem constants: ALPHA=0.5, MAX_COEFF=10, SHARPNESS=5
// N_VARS=1e6, N_CLAUSES=4e6, N_EDGES=12e6

constexpr int   N_CLAUSES_C = 4000000;
constexpr int   SB_SHIFT    = 12;                                        // 4096 clauses / sub-bucket
constexpr int   SB_CLS      = 1 << SB_SHIFT;
constexpr int   NSB         = (N_CLAUSES_C + SB_CLS - 1) >> SB_SHIFT;    // 977
constexpr int   SRT_CAP     = 13824;   // sub-bucket mean 12288, sd ~111; ~7 sigma
constexpr int   SC_THREADS  = 1024;
constexpr int   BATCH       = 8192;    // private region size (words)
constexpr int   NBATCH      = 3;
constexpr int   SC_CHUNK    = BATCH * NBATCH;   // 24576 -> 489 blocks
constexpr int   PR_THREADS  = 512;

typedef int v4i __attribute__((ext_vector_type(4)));

// ev encoding: top-20-bits-of-f32, round-to-nearest (proven R8-R11). RELATIVE
// err <= 2^-13 at every magnitude; exact for 0; monotone; ev<=1.0 -> 20 bits.
__device__ __forceinline__ uint32_t ev_enc(float ev) {
    return (__float_as_uint(ev) + 0x400u) >> 11;
}
__device__ __forceinline__ float ev_dec(uint32_t q) {
    return __uint_as_float(q << 11);
}

__device__ __forceinline__ void load_pair(const int* __restrict__ cls,
                                          const int* __restrict__ lits,
                                          int base, int c1, int (&cc)[8], int (&ll)[8]) {
    if (base + 8 <= c1) {
        v4i ca = __builtin_nontemporal_load((const v4i*)(cls  + base));
        v4i cb = __builtin_nontemporal_load((const v4i*)(cls  + base + 4));
        v4i la = __builtin_nontemporal_load((const v4i*)(lits + base));
        v4i lb = __builtin_nontemporal_load((const v4i*)(lits + base + 4));
        #pragma unroll
        for (int i = 0; i < 4; ++i) {
            cc[i] = ca[i]; cc[4 + i] = cb[i];
            ll[i] = la[i]; ll[4 + i] = lb[i];
        }
    } else {
        #pragma unroll
        for (int i = 0; i < 8; ++i) {
            int e = base + i;
            if (e < c1) { cc[i] = cls[e]; ll[i] = lits[e]; }
            else        { cc[i] = -1;     ll[i] = 0;       }
        }
    }
}

__device__ __forceinline__ void load_ef(const int* __restrict__ efi,
                                        int base, int c1, int (&ss)[8]) {
    if (base + 8 <= c1) {
        v4i fa = __builtin_nontemporal_load((const v4i*)(efi + base));
        v4i fb = __builtin_nontemporal_load((const v4i*)(efi + base + 4));
        #pragma unroll
        for (int i = 0; i < 4; ++i) { ss[i] = fa[i]; ss[4 + i] = fb[i]; }
    } else {
        #pragma unroll
        for (int i = 0; i < 8; ++i) { int e = base + i; ss[i] = (e < c1) ? efi[e] : 0; }
    }
}

// Phase A: block-private regions. Per batch k:
//   W: rank(k) (LDS u32 atomics) || LINEAR write-out(k-1)  -> B1
//   S: wave0 scans bh -> bOff; all waves prefetch cc(k+1)  -> B2
//   T: stage(k) via bOff; tbl row-write; zero bh            -> B3
// No global cursors, no bufB; payload written linearly (uint4, coalesced).
__global__ __launch_bounds__(SC_THREADS) void
scatter_kernel(const float* __restrict__ vp,
               const int* __restrict__ lits,
               const int* __restrict__ cls,
               const int* __restrict__ efi,      // ef as int bits (sign = -1)
               uint32_t* __restrict__ payload,   // [nprod][BATCH] private regions
               uint16_t* __restrict__ tbl,       // [NSB+1][npr] bOff table
               int n_edges, int npr) {
    __shared__ uint32_t bh[1024];         // sub-bucket histogram (zero-padded)
    __shared__ uint32_t bOff[1024];       // exclusive scan of bh
    __shared__ uint32_t buf[BATCH];       // staged packed entries (32 KB)

    const int tid  = threadIdx.x;
    const int lane = tid & 63;
    const int wv   = tid >> 6;
    const int c0   = blockIdx.x * SC_CHUNK;
    const int c1   = min(n_edges, c0 + SC_CHUNK);

    int cc[8], ll[8];
    uint32_t ent[8], pos[8];

    // prologue: batch-0 streams in flight while bh zeroes
    load_pair(cls, lits, c0 + tid * 8, c1, cc, ll);
    bh[tid] = 0;
    __syncthreads();

    for (int k = 0; k < NBATCH; ++k) {
        const int base = c0 + k * BATCH + tid * 8;
        const int prod = blockIdx.x * NBATCH + k;

        // ---- phase W: issue ef+gathers, rank(k); then write-out(k-1) ----
        int ss[8];
        load_ef(efi, base, c1, ss);
        float vv[8];
        #pragma unroll
        for (int i = 0; i < 8; ++i) vv[i] = (cc[i] >= 0) ? vp[ll[i]] : 0.0f;

        #pragma unroll
        for (int i = 0; i < 8; ++i) {
            pos[i] = 0xFFFFFFFFu;
            if (cc[i] >= 0) {
                uint32_t ib = (uint32_t)cc[i] >> SB_SHIFT;   // < 977
                uint32_t r  = atomicAdd(&bh[ib], 1u);
                if (r < 2048u) pos[i] = (ib << 11) | r;
            }
        }

        if (k > 0) {   // linear write-out of batch k-1 (full region, coalesced)
            const int basep = c0 + (k - 1) * BATCH;
            if (basep < n_edges) {
                uint4* dst = (uint4*)(payload + basep);
                const uint4* src = (const uint4*)buf;
                #pragma unroll
                for (int i = 0; i < 2; ++i) dst[tid + i * SC_THREADS] = src[tid + i * SC_THREADS];
            }
        }

        // packed entry (consumes gathers; latency hidden by rank+write-out)
        #pragma unroll
        for (int i = 0; i < 8; ++i) {
            if (pos[i] != 0xFFFFFFFFu) {
                float ev = (ss[i] >= 0) ? vv[i] : (1.0f - vv[i]);   // exact select
                ent[i] = (ev_enc(ev) << SB_SHIFT) | ((uint32_t)cc[i] & (SB_CLS - 1));
            }
        }
        __syncthreads();                           // B1

        // ---- phase S: wave0 scan; all waves prefetch next streams ----
        if (wv == 0) {
            const int jb = lane * 16;
            uint32_t t = 0;
            #pragma unroll
            for (int i = 0; i < 16; ++i) t += bh[jb + i];
            uint32_t x = t;
            #pragma unroll
            for (int d = 1; d < 64; d <<= 1) {
                uint32_t n = __shfl_up(x, (unsigned)d, 64);
                if (lane >= d) x += n;
            }
            uint32_t run = x - t;
            #pragma unroll
            for (int i = 0; i < 16; ++i) {
                uint32_t v = bh[jb + i];
                bOff[jb + i] = run;
                run += v;
            }
        }
        if (k + 1 < NBATCH)
            load_pair(cls, lits, c0 + (k + 1) * BATCH + tid * 8, c1, cc, ll);
        __syncthreads();                           // B2

        // ---- phase T: stage(k); table row write; zero bh ----
        #pragma unroll
        for (int i = 0; i < 8; ++i) {
            if (pos[i] != 0xFFFFFFFFu)
                buf[bOff[pos[i] >> 11] + (pos[i] & 2047u)] = ent[i];
        }
        if (tid <= NSB)   // rows 0..977; row NSB = totalS (bh tail zero-padded)
            tbl[(size_t)tid * npr + prod] = (uint16_t)bOff[tid];
        bh[tid] = 0;
        __syncthreads();                           // B3
    }

    // epilogue: write-out of the last batch
    const int basep = c0 + (NBATCH - 1) * BATCH;
    if (basep < n_edges) {
        uint4* dst = (uint4*)(payload + basep);
        const uint4* src = (const uint4*)buf;
        #pragma unroll
        for (int i = 0; i < 2; ++i) dst[tid + i * SC_THREADS] = src[tid + i * SC_THREADS];
    }
}

// Phase B: one block per 4096-clause sub-bucket. Reads per-producer segments
// via the u16 offset table; counting-sort in LDS (u32 atomics only); per-thread
// register accumulation — no fp atomics anywhere.
__global__ __launch_bounds__(PR_THREADS) void
process_kernel(const uint32_t* __restrict__ payload,
               const uint16_t* __restrict__ tbl,
               const float* __restrict__ gstep,
               const float* __restrict__ epsp,
               double* __restrict__ acc,
               int npr) {
    __shared__ uint32_t offp[SB_CLS / 2];    // 2 u16 counts per word, 8 KB
    __shared__ uint32_t srt[SRT_CAP];        // 55.3 KB
    __shared__ uint32_t wscan[8];
    __shared__ double   wsum[8];
    const int tid  = threadIdx.x;
    const int lane = tid & 63;
    const int wv   = tid >> 6;
    const int j    = blockIdx.x;             // sub-bucket id

    for (int i = tid; i < SB_CLS / 2; i += PR_THREADS) offp[i] = 0;
    __syncthreads();

    const uint16_t* row0 = tbl + (size_t)j * npr;
    const uint16_t* row1 = row0 + npr;

    // pass 1: clause histogram from segments (coalesced table reads)
    for (int pr = tid; pr < npr; pr += PR_THREADS) {
        int o0 = row0[pr], o1 = row1[pr];
        const uint32_t* seg = payload + (size_t)pr * BATCH + o0;
        for (int i = 0; i < o1 - o0; ++i) {
            uint32_t c = seg[i] & (SB_CLS - 1);
            atomicAdd(&offp[c >> 1], 1u << ((c & 1) << 4));
        }
    }
    __syncthreads();

    // in-place exclusive scan of 2048 packed-u16 words (thread owns 4 words)
    uint32_t pk[4];
    const int jb = tid * 4;
    uint32_t t = 0;
    #pragma unroll
    for (int i = 0; i < 4; ++i) {
        pk[i] = offp[jb + i];
        t += (pk[i] & 0xFFFFu) + (pk[i] >> 16);
    }
    uint32_t x = t;
    #pragma unroll
    for (int d = 1; d < 64; d <<= 1) {
        uint32_t n = __shfl_up(x, (unsigned)d, 64);
        if (lane >= d) x += n;
    }
    if (lane == 63) wscan[wv] = x;
    __syncthreads();
    if (tid == 0) {
        uint32_t r = 0;
        #pragma unroll
        for (int w = 0; w < 8; ++w) { uint32_t tm = wscan[w]; wscan[w] = r; r += tm; }
    }
    __syncthreads();
    uint32_t run = (x - t) + wscan[wv];
    #pragma unroll
    for (int i = 0; i < 4; ++i) {
        uint32_t lo = pk[i] & 0xFFFFu, hi = pk[i] >> 16;
        offp[jb + i] = run | ((run + lo) << 16);
        run += lo + hi;
    }
    __syncthreads();

    // pass 2: place entries clause-sorted (ds_add_rtn_u32 rank)
    for (int pr = tid; pr < npr; pr += PR_THREADS) {
        int o0 = row0[pr], o1 = row1[pr];
        const uint32_t* seg = payload + (size_t)pr * BATCH + o0;
        for (int i = 0; i < o1 - o0; ++i) {
            uint32_t p = seg[i];
            uint32_t c = p & (SB_CLS - 1);
            uint32_t sh = (c & 1) << 4;
            uint32_t r = atomicAdd(&offp[c >> 1], 1u << sh);
            uint32_t ps = (r >> sh) & 0xFFFFu;
            if (ps < (uint32_t)SRT_CAP) srt[ps] = p;
        }
    }
    __syncthreads();
    // offp half j == END of segment j; start(j) = end(j-1), start(0)=0

    // pass 3: per-clause register accumulation + log epilogue
    const float coeff = fminf(sqrtf(gstep[0]), 10.0f);
    const float eps   = epsp[0];
    const int gbase = j << SB_SHIFT;
    double local = 0.0;
    for (int c = tid; c < SB_CLS; c += PR_THREADS) {
        if (gbase + c < N_CLAUSES_C) {
            uint32_t e = (offp[c >> 1] >> ((c & 1) << 4)) & 0xFFFFu;
            uint32_t s = 0;
            if (c > 0) {
                int cm = c - 1;
                s = (offp[cm >> 1] >> ((cm & 1) << 4)) & 0xFFFFu;
            }
            e = min(e, (uint32_t)SRT_CAP);
            s = min(s, e);
            float nom = 0.f, den = 0.f;
            for (uint32_t i = s; i < e; ++i) {
                float ev = ev_dec(srt[i] >> SB_SHIFT);
                float w  = __expf(coeff * ev);
                nom = fmaf(w, ev, nom);
                den += w;
            }
            float cv = den / fmaxf(nom, eps);   // empty clause: 0/eps = 0 (ref-match)
            float tt = cv - 1.0f;
            float t2 = tt * tt;
            float cv2 = 1.0f + t2 * t2 * tt;    // 1 + (cv-1)^5
            local += (double)__logf(fmaxf(cv2, eps));
        }
    }
    #pragma unroll
    for (int off = 32; off > 0; off >>= 1) local += __shfl_down(local, off, 64);
    if (lane == 0) wsum[wv] = local;
    __syncthreads();
    if (tid == 0) {
        double s = 0.0;
        #pragma unroll
        for (int w = 0; w < 8; ++w) s += wsum[w];
        unsafeAtomicAdd(acc, s);
    }
}

__global__ void finalize_kernel(const double* __restrict__ acc,
                                const int* __restrict__ ncp,
                                float* __restrict__ out) {
    if (threadIdx.x == 0 && blockIdx.x == 0)
        out[0] = (float)(acc[0] / (double)ncp[0]);
}

extern "C" void kernel_launch(void* const* d_in, const int* in_sizes, int n_in,
                              void* d_out, int out_size, void* d_ws, size_t ws_size,
                              hipStream_t stream) {
    const float* vp    = (const float*)d_in[0];
    const int*   gmap  = (const int*)d_in[1];
    const float* ef    = (const float*)d_in[2];
    const int*   ncp   = (const int*)d_in[3];
    const float* gstep = (const float*)d_in[4];
    const float* epsp  = (const float*)d_in[5];
    float*       out   = (float*)d_out;

    const int n_edges = in_sizes[1] / 2;
    const int* lits = gmap;
    const int* cls  = gmap + n_edges;

    const int sc_blocks = (n_edges + SC_CHUNK - 1) / SC_CHUNK;   // 489
    const int npr       = sc_blocks * NBATCH;                    // 1467 (table cols)
    const int nprod_a   = (n_edges + BATCH - 1) / BATCH;         // 1465 (regions)

    // ws layout: payload | u16 table | f64 acc   (~50.9 MB total)
    uint32_t* payload = (uint32_t*)d_ws;
    size_t pay_words  = (size_t)nprod_a * BATCH;                 // 12,001,280
    uint16_t* tbl     = (uint16_t*)(payload + pay_words);
    size_t tbl_bytes  = (size_t)(NSB + 1) * npr * sizeof(uint16_t);
    size_t acc_off    = (pay_words * 4 + tbl_bytes + 7) & ~(size_t)7;
    double* acc       = (double*)((char*)d_ws + acc_off);

    // zero only the accumulator (table fully rewritten each call; payload
    // reads bounded by table)
    hipMemsetAsync(acc, 0, sizeof(double), stream);

    scatter_kernel<<<sc_blocks, SC_THREADS, 0, stream>>>(
        vp, lits, cls, (const int*)ef, payload, tbl, n_edges, npr);
    process_kernel<<<NSB, PR_THREADS, 0, stream>>>(
        payload, tbl, gstep, epsp, acc, npr);
    finalize_kernel<<<1, 64, 0, stream>>>(acc, ncp, out);
}

// Round 16
// 166.500 us; speedup vs baseline: 1.5133x; 1.5133x over previous
//
#include <hip/hip_runtime.h>
#include <math.h>

// Problem constants: ALPHA=0.5, MAX_COEFF=10, SHARPNESS=5
// N_VARS=1e6, N_CLAUSES=4e6, N_EDGES=12e6

constexpr int   N_CLAUSES_C = 4000000;
constexpr int   BKT_SHIFT   = 13;                                        // 8192 clauses / coarse bucket
constexpr int   BKT_CLS     = 1 << BKT_SHIFT;
constexpr int   NB_TOTAL    = (N_CLAUSES_C + BKT_CLS - 1) >> BKT_SHIFT;  // 489
constexpr int   CAP         = 25728;   // mean 24576, sd ~157; ~7 sigma
constexpr int   SUB_CLS     = 4096;    // process granularity (half a coarse bucket)
constexpr int   SRT_CAP     = 13824;   // sub-bucket mean 12288 + 7 sigma + pad
constexpr int   SC_THREADS  = 1024;
constexpr int   BATCH       = 8192;    // runs ~16.8 words (~67B) with 489 buckets
constexpr int   NBATCH      = 3;
constexpr int   SC_CHUNK    = BATCH * NBATCH;   // 24576 -> 489 blocks
constexpr int   PR_THREADS  = 512;

typedef int v4i __attribute__((ext_vector_type(4)));

// ev encoding: top-19-bits-of-f32 with round-to-nearest. RELATIVE err <= 2^-12
// at every magnitude (linear quant zeroed tiny ev -> cv=den/nom -> inf).
// Exact for 0; monotone; ev<=1.0 -> 0x3F800 < 2^19.
__device__ __forceinline__ uint32_t ev_enc(float ev) {
    return (__float_as_uint(ev) + 0x800u) >> 12;
}
__device__ __forceinline__ float ev_dec(uint32_t q) {
    return __uint_as_float(q << 12);
}

__device__ __forceinline__ void load_pair(const int* __restrict__ cls,
                                          const int* __restrict__ lits,
                                          int base, int c1, int (&cc)[8], int (&ll)[8]) {
    if (base + 8 <= c1) {
        v4i ca = __builtin_nontemporal_load((const v4i*)(cls  + base));
        v4i cb = __builtin_nontemporal_load((const v4i*)(cls  + base + 4));
        v4i la = __builtin_nontemporal_load((const v4i*)(lits + base));
        v4i lb = __builtin_nontemporal_load((const v4i*)(lits + base + 4));
        #pragma unroll
        for (int i = 0; i < 4; ++i) {
            cc[i] = ca[i]; cc[4 + i] = cb[i];
            ll[i] = la[i]; ll[4 + i] = lb[i];
        }
    } else {
        #pragma unroll
        for (int i = 0; i < 8; ++i) {
            int e = base + i;
            if (e < c1) { cc[i] = cls[e]; ll[i] = lits[e]; }
            else        { cc[i] = -1;     ll[i] = 0;       }
        }
    }
}

__device__ __forceinline__ void load_ef(const int* __restrict__ efi,
                                        int base, int c1, int (&ss)[8]) {
    if (base + 8 <= c1) {
        v4i fa = __builtin_nontemporal_load((const v4i*)(efi + base));
        v4i fb = __builtin_nontemporal_load((const v4i*)(efi + base + 4));
        #pragma unroll
        for (int i = 0; i < 4; ++i) { ss[i] = fa[i]; ss[4 + i] = fb[i]; }
    } else {
        #pragma unroll
        for (int i = 0; i < 8; ++i) { int e = base + i; ss[i] = (e < c1) ? efi[e] : 0; }
    }
}

// Phase A: 3-barrier software-pipelined batches (R14 structure, best measured).
// steady state per batch k:
//   {wave0: scan bh | waves1-15: claim bb}            -> B
//   {stage(k) from meta/ss/vv; zero bh; prefetch cc}  -> B
//   {issue ef/gathers(k+1); rank(k+1) -> bh,meta  ||  write-out(k)} -> B
__global__ __launch_bounds__(SC_THREADS) void
scatter_kernel(const float* __restrict__ vp,
               const int* __restrict__ lits,
               const int* __restrict__ cls,
               const int* __restrict__ efi,     // ef as int bits (sign = -1)
               uint32_t* __restrict__ payload,  // [nbp][CAP]
               uint32_t* __restrict__ cursors,  // [NB_TOTAL], zeroed
               int n_edges, int b_lo, int b_hi) {
    __shared__ uint32_t bh[512];          // padded histogram
    __shared__ uint32_t bOff[512];        // exclusive scan of bh (LDS base)
    __shared__ uint32_t bb[512];          // per-batch claimed global base
    __shared__ uint32_t buf[BATCH];       // staged packed entries (32 KB)
    __shared__ uint16_t bufB[BATCH];      // staged bucket ids (16 KB)
    __shared__ uint32_t totalS;

    const int tid  = threadIdx.x;
    const int lane = tid & 63;
    const int wv   = tid >> 6;
    const int nbp  = b_hi - b_lo;         // <= 489
    const int c0   = blockIdx.x * SC_CHUNK;
    const int c1   = min(n_edges, c0 + SC_CHUNK);
    const int nb   = (c1 - c0 + BATCH - 1) / BATCH;   // block-uniform

    int cc[8], ll[8], ss[8];
    float vv[8];
    uint32_t meta[8];

    // prologue: load batch-0 streams, zero bh
    load_pair(cls, lits, c0 + tid * 8, c1, cc, ll);
    if (tid < 512) bh[tid] = 0;
    __syncthreads();

    // prologue rank(0): issue ef+gathers, rank into bh/meta
    load_ef(efi, c0 + tid * 8, c1, ss);
    #pragma unroll
    for (int i = 0; i < 8; ++i) vv[i] = (cc[i] >= 0) ? vp[ll[i]] : 0.0f;
    #pragma unroll
    for (int i = 0; i < 8; ++i) {
        meta[i] = 0xFF800000u;                 // ib=511 -> invalid
        if (cc[i] >= 0) {
            int b = cc[i] >> BKT_SHIFT;
            if (b >= b_lo && b < b_hi) {
                uint32_t ib = (uint32_t)(b - b_lo);
                uint32_t r  = atomicAdd(&bh[ib], 1u);
                if (r < 1024u)
                    meta[i] = ((uint32_t)cc[i] & 8191u) | (r << 13) | (ib << 23);
            }
        }
    }
    __syncthreads();

    for (int k = 0; k < nb; ++k) {
        // phase S: wave0 scans bh -> bOff/totalS; other waves claim global runs
        if (wv == 0) {
            const int jb = lane * 8;
            uint32_t t = 0;
            #pragma unroll
            for (int i = 0; i < 8; ++i) t += bh[jb + i];
            uint32_t x = t;
            #pragma unroll
            for (int d = 1; d < 64; d <<= 1) {
                uint32_t n = __shfl_up(x, (unsigned)d, 64);
                if (lane >= d) x += n;
            }
            uint32_t run = x - t;
            #pragma unroll
            for (int i = 0; i < 8; ++i) {
                uint32_t v = bh[jb + i];
                bOff[jb + i] = run;
                run += v;
            }
            if (lane == 63) totalS = x;
        } else {
            for (int i = tid - 64; i < nbp; i += SC_THREADS - 64) {
                uint32_t v = bh[i];
                bb[i] = v ? atomicAdd(&cursors[b_lo + i], v) : 0u;
            }
        }
        __syncthreads();                           // B1

        // phase T: stage(k) into bucket-grouped LDS; zero bh; prefetch cc(k+1)
        #pragma unroll
        for (int i = 0; i < 8; ++i) {
            uint32_t ib = meta[i] >> 23;
            if (ib < 511u) {
                float ev = (ss[i] >= 0) ? vv[i] : (1.0f - vv[i]);
                uint32_t s = bOff[ib] + ((meta[i] >> 13) & 1023u);
                buf[s]  = (ev_enc(ev) << BKT_SHIFT) | (meta[i] & 8191u);
                bufB[s] = (uint16_t)ib;
            }
        }
        if (tid < 512) bh[tid] = 0;
        if (k + 1 < nb)
            load_pair(cls, lits, c0 + (k + 1) * BATCH + tid * 8, c1, cc, ll);
        __syncthreads();                           // B2

        // phase W: rank(k+1) (bh/cc only) overlapped with write-out(k)
        if (k + 1 < nb) {
            load_ef(efi, c0 + (k + 1) * BATCH + tid * 8, c1, ss);
            #pragma unroll
            for (int i = 0; i < 8; ++i) vv[i] = (cc[i] >= 0) ? vp[ll[i]] : 0.0f;
            #pragma unroll
            for (int i = 0; i < 8; ++i) {
                meta[i] = 0xFF800000u;
                if (cc[i] >= 0) {
                    int b = cc[i] >> BKT_SHIFT;
                    if (b >= b_lo && b < b_hi) {
                        uint32_t ib = (uint32_t)(b - b_lo);
                        uint32_t r  = atomicAdd(&bh[ib], 1u);
                        if (r < 1024u)
                            meta[i] = ((uint32_t)cc[i] & 8191u) | (r << 13) | (ib << 23);
                    }
                }
            }
        }
        // linear coalesced write-out(k): all lanes store every iteration
        const uint32_t tS = totalS;
        for (uint32_t s = tid; s < tS; s += SC_THREADS) {
            uint32_t ib   = bufB[s];
            uint32_t gpos = bb[ib] + (s - bOff[ib]);
            if (gpos < (uint32_t)CAP)
                payload[(size_t)ib * CAP + gpos] = buf[s];
        }
        __syncthreads();                           // B3
    }
}

// Phase B: TWO blocks per coarse bucket (same-XCD pair via swizzle); each
// filters its 4096-clause half, counting-sorts it in LDS (u32 atomics only),
// then per-thread register accumulation — no fp atomics anywhere.
__global__ __launch_bounds__(PR_THREADS) void
process_kernel(const uint32_t* __restrict__ payload,
               const uint32_t* __restrict__ cursors,
               const float* __restrict__ gstep,
               const float* __restrict__ epsp,
               double* __restrict__ acc,
               int b_lo, int nbp) {
    __shared__ uint32_t offp[SUB_CLS / 2];   // 2 u16 counts per word, 8 KB
    __shared__ uint32_t srt[SRT_CAP];        // 55.3 KB
    __shared__ uint32_t wscan[8];
    __shared__ double   wsum[8];
    const int tid  = threadIdx.x;
    const int lane = tid & 63;
    const int wv   = tid >> 6;

    // swizzle: bid = 16q + r; coarse = q*8 + (r&7), half = r>>3.
    // halves of one coarse bucket land on the SAME XCD (bid%8 equal) -> L2 share.
    const int bid = blockIdx.x;
    const int ibc = (bid >> 4) * 8 + (bid & 7);
    const int half = (bid >> 3) & 1;
    if (ibc >= nbp) return;
    const int b = b_lo + ibc;
    const uint32_t hmask = (uint32_t)half << 12;

    for (int j = tid; j < SUB_CLS / 2; j += PR_THREADS) offp[j] = 0;
    __syncthreads();

    const uint32_t cnt = min(cursors[b], (uint32_t)CAP);
    const uint32_t* pl = payload + (size_t)ibc * CAP;
    const uint32_t nv = cnt >> 2;

    // pass 1: histogram of this half's clauses (packed u16 halves)
    for (uint32_t k = tid; k < nv; k += PR_THREADS) {
        uint4 p4 = ((const uint4*)pl)[k];
        #pragma unroll
        for (int j = 0; j < 4; ++j) {
            uint32_t p = (j == 0) ? p4.x : (j == 1) ? p4.y : (j == 2) ? p4.z : p4.w;
            if ((p & 4096u) == hmask) {
                uint32_t c = p & 4095u;
                atomicAdd(&offp[c >> 1], 1u << ((c & 1) << 4));
            }
        }
    }
    for (uint32_t k = (nv << 2) + tid; k < cnt; k += PR_THREADS) {
        uint32_t p = pl[k];
        if ((p & 4096u) == hmask) {
            uint32_t c = p & 4095u;
            atomicAdd(&offp[c >> 1], 1u << ((c & 1) << 4));
        }
    }
    __syncthreads();

    // in-place exclusive scan of 2048 packed-u16 words (thread owns 4 words)
    uint32_t pk[4];
    const int jb = tid * 4;
    uint32_t t = 0;
    #pragma unroll
    for (int i = 0; i < 4; ++i) {
        pk[i] = offp[jb + i];
        t += (pk[i] & 0xFFFFu) + (pk[i] >> 16);
    }
    uint32_t x = t;
    #pragma unroll
    for (int d = 1; d < 64; d <<= 1) {
        uint32_t n = __shfl_up(x, (unsigned)d, 64);
        if (lane >= d) x += n;
    }
    if (lane == 63) wscan[wv] = x;
    __syncthreads();
    if (tid == 0) {
        uint32_t r = 0;
        #pragma unroll
        for (int w = 0; w < 8; ++w) { uint32_t tm = wscan[w]; wscan[w] = r; r += tm; }
    }
    __syncthreads();
    uint32_t run = (x - t) + wscan[wv];
    #pragma unroll
    for (int i = 0; i < 4; ++i) {
        uint32_t lo = pk[i] & 0xFFFFu, hi = pk[i] >> 16;
        offp[jb + i] = run | ((run + lo) << 16);
        run += lo + hi;
    }
    __syncthreads();

    // pass 2: place this half's entries clause-sorted (ds_add_rtn_u32 rank)
    for (uint32_t k = tid; k < nv; k += PR_THREADS) {
        uint4 p4 = ((const uint4*)pl)[k];
        #pragma unroll
        for (int j = 0; j < 4; ++j) {
            uint32_t p = (j == 0) ? p4.x : (j == 1) ? p4.y : (j == 2) ? p4.z : p4.w;
            if ((p & 4096u) == hmask) {
                uint32_t c = p & 4095u;
                uint32_t sh = (c & 1) << 4;
                uint32_t r = atomicAdd(&offp[c >> 1], 1u << sh);
                uint32_t pos = (r >> sh) & 0xFFFFu;
                if (pos < (uint32_t)SRT_CAP) srt[pos] = p;
            }
        }
    }
    for (uint32_t k = (nv << 2) + tid; k < cnt; k += PR_THREADS) {
        uint32_t p = pl[k];
        if ((p & 4096u) == hmask) {
            uint32_t c = p & 4095u;
            uint32_t sh = (c & 1) << 4;
            uint32_t r = atomicAdd(&offp[c >> 1], 1u << sh);
            uint32_t pos = (r >> sh) & 0xFFFFu;
            if (pos < (uint32_t)SRT_CAP) srt[pos] = p;
        }
    }
    __syncthreads();
    // offp half j == END of segment j; start(j) = end(j-1), start(0)=0

    // pass 3: per-clause register accumulation + log epilogue
    const float coeff = fminf(sqrtf(gstep[0]), 10.0f);
    const float eps   = epsp[0];
    const int gbase = (b << BKT_SHIFT) + (half << 12);
    double local = 0.0;
    for (int j = tid; j < SUB_CLS; j += PR_THREADS) {
        if (gbase + j < N_CLAUSES_C) {
            uint32_t e = (offp[j >> 1] >> ((j & 1) << 4)) & 0xFFFFu;
            uint32_t s = 0;
            if (j > 0) {
                int jm = j - 1;
                s = (offp[jm >> 1] >> ((jm & 1) << 4)) & 0xFFFFu;
            }
            e = min(e, (uint32_t)SRT_CAP);
            s = min(s, e);
            float nom = 0.f, den = 0.f;
            for (uint32_t k = s; k < e; ++k) {
                float ev = ev_dec(srt[k] >> BKT_SHIFT);
                float w  = __expf(coeff * ev);
                nom = fmaf(w, ev, nom);
                den += w;
            }
            float cv = den / fmaxf(nom, eps);   // empty clause: 0/eps = 0 (ref-match)
            float tt = cv - 1.0f;
            float t2 = tt * tt;
            float cv2 = 1.0f + t2 * t2 * tt;    // 1 + (cv-1)^5
            local += (double)__logf(fmaxf(cv2, eps));
        }
    }
    #pragma unroll
    for (int off = 32; off > 0; off >>= 1) local += __shfl_down(local, off, 64);
    if (lane == 0) wsum[wv] = local;
    __syncthreads();
    if (tid == 0) {
        double s = 0.0;
        #pragma unroll
        for (int w = 0; w < 8; ++w) s += wsum[w];
        unsafeAtomicAdd(acc, s);
    }
}

__global__ void finalize_kernel(const double* __restrict__ acc,
                                const int* __restrict__ ncp,
                                float* __restrict__ out) {
    if (threadIdx.x == 0 && blockIdx.x == 0)
        out[0] = (float)(acc[0] / (double)ncp[0]);
}

extern "C" void kernel_launch(void* const* d_in, const int* in_sizes, int n_in,
                              void* d_out, int out_size, void* d_ws, size_t ws_size,
                              hipStream_t stream) {
    const float* vp    = (const float*)d_in[0];
    const int*   gmap  = (const int*)d_in[1];
    const float* ef    = (const float*)d_in[2];
    const int*   ncp   = (const int*)d_in[3];
    const float* gstep = (const float*)d_in[4];
    const float* epsp  = (const float*)d_in[5];
    float*       out   = (float*)d_out;

    const int n_edges = in_sizes[1] / 2;
    const int* lits = gmap;
    const int* cls  = gmap + n_edges;

    // choose pass count so payload fits the workspace (P=1 needs ~50.3MB)
    int P = 8;
    int nbp_max = (NB_TOTAL + 7) / 8;
    size_t cursors_off_w = (size_t)nbp_max * CAP;
    size_t acc_off_w = (cursors_off_w + NB_TOTAL + 1) & ~(size_t)1;
    const int cands[4] = {1, 2, 4, 8};
    for (int ci = 0; ci < 4; ++ci) {
        int cand = cands[ci];
        int nm = (NB_TOTAL + cand - 1) / cand;
        size_t pw = (size_t)nm * CAP;
        size_t cw = pw + NB_TOTAL;
        size_t aw = (cw + 1) & ~(size_t)1;
        size_t need = aw * 4 + 8;
        if (need <= ws_size) { P = cand; nbp_max = nm; cursors_off_w = pw; acc_off_w = aw; break; }
    }

    uint32_t* payload = (uint32_t*)d_ws;
    uint32_t* cursors = payload + cursors_off_w;
    double*   acc     = (double*)((uint32_t*)d_ws + acc_off_w);

    // zero cursors + accumulator every call (ws is poisoned, not re-zeroed)
    hipMemsetAsync(cursors, 0, (acc_off_w - cursors_off_w) * 4 + 8, stream);

    const int sc_blocks = (n_edges + SC_CHUNK - 1) / SC_CHUNK;  // 489 for 12M
    for (int p = 0; p < P; ++p) {
        int b_lo = p * nbp_max;
        int b_hi = min(NB_TOTAL, b_lo + nbp_max);
        if (b_lo >= b_hi) continue;
        int nbp = b_hi - b_lo;
        scatter_kernel<<<sc_blocks, SC_THREADS, 0, stream>>>(
            vp, lits, cls, (const int*)ef, payload, cursors, n_edges, b_lo, b_hi);
        int pr_grid = ((2 * nbp + 15) / 16) * 16;   // swizzle-friendly rounding
        process_kernel<<<pr_grid, PR_THREADS, 0, stream>>>(
            payload, cursors, gstep, epsp, acc, b_lo, nbp);
    }
    finalize_kernel<<<1, 64, 0, stream>>>(acc, ncp, out);
}

// Round 17
// 156.326 us; speedup vs baseline: 1.6118x; 1.0651x over previous
//
#include <hip/hip_runtime.h>
#include <math.h>

// Problem constants: ALPHA=0.5, MAX_COEFF=10, SHARPNESS=5
// N_VARS=1e6, N_CLAUSES=4e6, N_EDGES=12e6

constexpr int   N_CLAUSES_C = 4000000;
constexpr int   BKT_SHIFT   = 13;                                        // 8192 clauses / coarse bucket
constexpr int   BKT_CLS     = 1 << BKT_SHIFT;
constexpr int   NB_TOTAL    = (N_CLAUSES_C + BKT_CLS - 1) >> BKT_SHIFT;  // 489
constexpr int   CAP         = 25728;   // mean 24576, sd ~157; ~7 sigma
constexpr int   SC_THREADS  = 1024;
constexpr int   BATCH       = 8192;    // runs ~16.8 words (~67B) with 489 buckets
constexpr int   NBATCH      = 3;
constexpr int   SC_CHUNK    = BATCH * NBATCH;   // 24576 -> 489 blocks
constexpr int   PR_THREADS  = 1024;

typedef int v4i __attribute__((ext_vector_type(4)));

// ev encoding: top-19-bits-of-f32 with round-to-nearest. RELATIVE err <= 2^-12
// at every magnitude (linear quant zeroed tiny ev -> cv=den/nom -> inf).
// Exact for 0; monotone; ev<=1.0 -> 0x3F800 < 2^19.
__device__ __forceinline__ uint32_t ev_enc(float ev) {
    return (__float_as_uint(ev) + 0x800u) >> 12;
}
__device__ __forceinline__ float ev_dec(uint32_t q) {
    return __uint_as_float(q << 12);
}

__device__ __forceinline__ void load_pair(const int* __restrict__ cls,
                                          const int* __restrict__ lits,
                                          int base, int c1, int (&cc)[8], int (&ll)[8]) {
    if (base + 8 <= c1) {
        v4i ca = __builtin_nontemporal_load((const v4i*)(cls  + base));
        v4i cb = __builtin_nontemporal_load((const v4i*)(cls  + base + 4));
        v4i la = __builtin_nontemporal_load((const v4i*)(lits + base));
        v4i lb = __builtin_nontemporal_load((const v4i*)(lits + base + 4));
        #pragma unroll
        for (int i = 0; i < 4; ++i) {
            cc[i] = ca[i]; cc[4 + i] = cb[i];
            ll[i] = la[i]; ll[4 + i] = lb[i];
        }
    } else {
        #pragma unroll
        for (int i = 0; i < 8; ++i) {
            int e = base + i;
            if (e < c1) { cc[i] = cls[e]; ll[i] = lits[e]; }
            else        { cc[i] = -1;     ll[i] = 0;       }
        }
    }
}

__device__ __forceinline__ void load_ef(const int* __restrict__ efi,
                                        int base, int c1, int (&ss)[8]) {
    if (base + 8 <= c1) {
        v4i fa = __builtin_nontemporal_load((const v4i*)(efi + base));
        v4i fb = __builtin_nontemporal_load((const v4i*)(efi + base + 4));
        #pragma unroll
        for (int i = 0; i < 4; ++i) { ss[i] = fa[i]; ss[4 + i] = fb[i]; }
    } else {
        #pragma unroll
        for (int i = 0; i < 8; ++i) { int e = base + i; ss[i] = (e < c1) ? efi[e] : 0; }
    }
}

// Phase A: 3-barrier software-pipelined batches (R14 structure, best measured).
// steady state per batch k:
//   {wave0: scan bh | waves1-15: claim bb}            -> B
//   {stage(k) from meta/ss/vv; zero bh; prefetch cc}  -> B
//   {issue ef/gathers(k+1); rank(k+1) -> bh,meta  ||  write-out(k)} -> B
__global__ __launch_bounds__(SC_THREADS) void
scatter_kernel(const float* __restrict__ vp,
               const int* __restrict__ lits,
               const int* __restrict__ cls,
               const int* __restrict__ efi,     // ef as int bits (sign = -1)
               uint32_t* __restrict__ payload,  // [nbp][CAP]
               uint32_t* __restrict__ cursors,  // [NB_TOTAL], zeroed
               int n_edges, int b_lo, int b_hi) {
    __shared__ uint32_t bh[512];          // padded histogram
    __shared__ uint32_t bOff[512];        // exclusive scan of bh (LDS base)
    __shared__ uint32_t bb[512];          // per-batch claimed global base
    __shared__ uint32_t buf[BATCH];       // staged packed entries (32 KB)
    __shared__ uint16_t bufB[BATCH];      // staged bucket ids (16 KB)
    __shared__ uint32_t totalS;

    const int tid  = threadIdx.x;
    const int lane = tid & 63;
    const int wv   = tid >> 6;
    const int nbp  = b_hi - b_lo;         // <= 489
    const int c0   = blockIdx.x * SC_CHUNK;
    const int c1   = min(n_edges, c0 + SC_CHUNK);
    const int nb   = (c1 - c0 + BATCH - 1) / BATCH;   // block-uniform

    int cc[8], ll[8], ss[8];
    float vv[8];
    uint32_t meta[8];

    // prologue: load batch-0 streams, zero bh
    load_pair(cls, lits, c0 + tid * 8, c1, cc, ll);
    if (tid < 512) bh[tid] = 0;
    __syncthreads();

    // prologue rank(0): issue ef+gathers, rank into bh/meta
    load_ef(efi, c0 + tid * 8, c1, ss);
    #pragma unroll
    for (int i = 0; i < 8; ++i) vv[i] = (cc[i] >= 0) ? vp[ll[i]] : 0.0f;
    #pragma unroll
    for (int i = 0; i < 8; ++i) {
        meta[i] = 0xFF800000u;                 // ib=511 -> invalid
        if (cc[i] >= 0) {
            int b = cc[i] >> BKT_SHIFT;
            if (b >= b_lo && b < b_hi) {
                uint32_t ib = (uint32_t)(b - b_lo);
                uint32_t r  = atomicAdd(&bh[ib], 1u);
                if (r < 1024u)
                    meta[i] = ((uint32_t)cc[i] & 8191u) | (r << 13) | (ib << 23);
            }
        }
    }
    __syncthreads();

    for (int k = 0; k < nb; ++k) {
        // phase S: wave0 scans bh -> bOff/totalS; other waves claim global runs
        if (wv == 0) {
            const int jb = lane * 8;
            uint32_t t = 0;
            #pragma unroll
            for (int i = 0; i < 8; ++i) t += bh[jb + i];
            uint32_t x = t;
            #pragma unroll
            for (int d = 1; d < 64; d <<= 1) {
                uint32_t n = __shfl_up(x, (unsigned)d, 64);
                if (lane >= d) x += n;
            }
            uint32_t run = x - t;
            #pragma unroll
            for (int i = 0; i < 8; ++i) {
                uint32_t v = bh[jb + i];
                bOff[jb + i] = run;
                run += v;
            }
            if (lane == 63) totalS = x;
        } else {
            for (int i = tid - 64; i < nbp; i += SC_THREADS - 64) {
                uint32_t v = bh[i];
                bb[i] = v ? atomicAdd(&cursors[b_lo + i], v) : 0u;
            }
        }
        __syncthreads();                           // B1

        // phase T: stage(k) into bucket-grouped LDS; zero bh; prefetch cc(k+1)
        #pragma unroll
        for (int i = 0; i < 8; ++i) {
            uint32_t ib = meta[i] >> 23;
            if (ib < 511u) {
                float ev = (ss[i] >= 0) ? vv[i] : (1.0f - vv[i]);
                uint32_t s = bOff[ib] + ((meta[i] >> 13) & 1023u);
                buf[s]  = (ev_enc(ev) << BKT_SHIFT) | (meta[i] & 8191u);
                bufB[s] = (uint16_t)ib;
            }
        }
        if (tid < 512) bh[tid] = 0;
        if (k + 1 < nb)
            load_pair(cls, lits, c0 + (k + 1) * BATCH + tid * 8, c1, cc, ll);
        __syncthreads();                           // B2

        // phase W: rank(k+1) (bh/cc only) overlapped with write-out(k)
        if (k + 1 < nb) {
            load_ef(efi, c0 + (k + 1) * BATCH + tid * 8, c1, ss);
            #pragma unroll
            for (int i = 0; i < 8; ++i) vv[i] = (cc[i] >= 0) ? vp[ll[i]] : 0.0f;
            #pragma unroll
            for (int i = 0; i < 8; ++i) {
                meta[i] = 0xFF800000u;
                if (cc[i] >= 0) {
                    int b = cc[i] >> BKT_SHIFT;
                    if (b >= b_lo && b < b_hi) {
                        uint32_t ib = (uint32_t)(b - b_lo);
                        uint32_t r  = atomicAdd(&bh[ib], 1u);
                        if (r < 1024u)
                            meta[i] = ((uint32_t)cc[i] & 8191u) | (r << 13) | (ib << 23);
                    }
                }
            }
        }
        // linear coalesced write-out(k): all lanes store every iteration
        const uint32_t tS = totalS;
        for (uint32_t s = tid; s < tS; s += SC_THREADS) {
            uint32_t ib   = bufB[s];
            uint32_t gpos = bb[ib] + (s - bOff[ib]);
            if (gpos < (uint32_t)CAP)
                payload[(size_t)ib * CAP + gpos] = buf[s];
        }
        __syncthreads();                           // B3
    }
}

// Phase B: ONE 1024-thread block per coarse bucket (8192 clauses). Payload
// read ONCE. Counting-sort in LDS (u32 atomics only; offp 16 KB + srt 100.5 KB
// = 119.5 KB — legal on gfx950, cf. HK 128 KiB workgroups), then per-thread
// register accumulation — no fp atomics anywhere.
__global__ __launch_bounds__(PR_THREADS) void
process_kernel(const uint32_t* __restrict__ payload,
               const uint32_t* __restrict__ cursors,
               const float* __restrict__ gstep,
               const float* __restrict__ epsp,
               double* __restrict__ acc,
               int b_lo, int nbp) {
    __shared__ uint32_t offp[BKT_CLS / 2];   // 2 u16 counts per word, 16 KB
    __shared__ uint32_t srt[CAP];            // 100.5 KB
    __shared__ uint32_t wscan[16];
    __shared__ double   wsum[16];
    const int tid  = threadIdx.x;
    const int lane = tid & 63;
    const int wv   = tid >> 6;
    const int ibc  = blockIdx.x;
    if (ibc >= nbp) return;
    const int b = b_lo + ibc;

    for (int j = tid; j < BKT_CLS / 2; j += PR_THREADS) offp[j] = 0;
    __syncthreads();

    const uint32_t cnt = min(cursors[b], (uint32_t)CAP);
    const uint32_t* pl = payload + (size_t)ibc * CAP;
    const uint32_t nv = cnt >> 2;

    // pass 1: clause histogram (packed u16 halves; counts, positions < 2^16)
    for (uint32_t k = tid; k < nv; k += PR_THREADS) {
        uint4 p4 = ((const uint4*)pl)[k];
        uint32_t c;
        c = p4.x & (BKT_CLS - 1); atomicAdd(&offp[c >> 1], 1u << ((c & 1) << 4));
        c = p4.y & (BKT_CLS - 1); atomicAdd(&offp[c >> 1], 1u << ((c & 1) << 4));
        c = p4.z & (BKT_CLS - 1); atomicAdd(&offp[c >> 1], 1u << ((c & 1) << 4));
        c = p4.w & (BKT_CLS - 1); atomicAdd(&offp[c >> 1], 1u << ((c & 1) << 4));
    }
    for (uint32_t k = (nv << 2) + tid; k < cnt; k += PR_THREADS) {
        uint32_t c = pl[k] & (BKT_CLS - 1);
        atomicAdd(&offp[c >> 1], 1u << ((c & 1) << 4));
    }
    __syncthreads();

    // in-place exclusive scan of 4096 packed-u16 words (thread owns 4 words)
    uint32_t pk[4];
    const int jb = tid * 4;
    uint32_t t = 0;
    #pragma unroll
    for (int i = 0; i < 4; ++i) {
        pk[i] = offp[jb + i];
        t += (pk[i] & 0xFFFFu) + (pk[i] >> 16);
    }
    uint32_t x = t;
    #pragma unroll
    for (int d = 1; d < 64; d <<= 1) {
        uint32_t n = __shfl_up(x, (unsigned)d, 64);
        if (lane >= d) x += n;
    }
    if (lane == 63) wscan[wv] = x;
    __syncthreads();
    if (tid == 0) {
        uint32_t r = 0;
        #pragma unroll
        for (int w = 0; w < 16; ++w) { uint32_t tm = wscan[w]; wscan[w] = r; r += tm; }
    }
    __syncthreads();
    uint32_t run = (x - t) + wscan[wv];
    #pragma unroll
    for (int i = 0; i < 4; ++i) {
        uint32_t lo = pk[i] & 0xFFFFu, hi = pk[i] >> 16;
        offp[jb + i] = run | ((run + lo) << 16);   // both starts <= cnt < 2^16
        run += lo + hi;
    }
    __syncthreads();

    // pass 2: place entries clause-sorted (ds_add_rtn_u32 rank)
    for (uint32_t k = tid; k < nv; k += PR_THREADS) {
        uint4 p4 = ((const uint4*)pl)[k];
        #pragma unroll
        for (int j = 0; j < 4; ++j) {
            uint32_t p = (j == 0) ? p4.x : (j == 1) ? p4.y : (j == 2) ? p4.z : p4.w;
            uint32_t c = p & (BKT_CLS - 1);
            uint32_t sh = (c & 1) << 4;
            uint32_t r = atomicAdd(&offp[c >> 1], 1u << sh);
            uint32_t pos = (r >> sh) & 0xFFFFu;
            if (pos < (uint32_t)CAP) srt[pos] = p;
        }
    }
    for (uint32_t k = (nv << 2) + tid; k < cnt; k += PR_THREADS) {
        uint32_t p = pl[k];
        uint32_t c = p & (BKT_CLS - 1);
        uint32_t sh = (c & 1) << 4;
        uint32_t r = atomicAdd(&offp[c >> 1], 1u << sh);
        uint32_t pos = (r >> sh) & 0xFFFFu;
        if (pos < (uint32_t)CAP) srt[pos] = p;
    }
    __syncthreads();
    // offp half j == END of segment j; start(j) = end(j-1), start(0)=0

    // pass 3: per-clause register accumulation + log epilogue
    const float coeff = fminf(sqrtf(gstep[0]), 10.0f);
    const float eps   = epsp[0];
    const int gbase = b << BKT_SHIFT;
    double local = 0.0;
    for (int j = tid; j < BKT_CLS; j += PR_THREADS) {
        if (gbase + j < N_CLAUSES_C) {
            uint32_t e = (offp[j >> 1] >> ((j & 1) << 4)) & 0xFFFFu;
            uint32_t s = 0;
            if (j > 0) {
                int jm = j - 1;
                s = (offp[jm >> 1] >> ((jm & 1) << 4)) & 0xFFFFu;
            }
            e = min(e, (uint32_t)CAP);
            s = min(s, e);
            float nom = 0.f, den = 0.f;
            for (uint32_t k = s; k < e; ++k) {
                float ev = ev_dec(srt[k] >> BKT_SHIFT);
                float w  = __expf(coeff * ev);
                nom = fmaf(w, ev, nom);
                den += w;
            }
            float cv = den / fmaxf(nom, eps);   // empty clause: 0/eps = 0 (ref-match)
            float tt = cv - 1.0f;
            float t2 = tt * tt;
            float cv2 = 1.0f + t2 * t2 * tt;    // 1 + (cv-1)^5
            local += (double)__logf(fmaxf(cv2, eps));
        }
    }
    #pragma unroll
    for (int off = 32; off > 0; off >>= 1) local += __shfl_down(local, off, 64);
    if (lane == 0) wsum[wv] = local;
    __syncthreads();
    if (tid == 0) {
        double s = 0.0;
        #pragma unroll
        for (int w = 0; w < 16; ++w) s += wsum[w];
        unsafeAtomicAdd(acc, s);
    }
}

__global__ void finalize_kernel(const double* __restrict__ acc,
                                const int* __restrict__ ncp,
                                float* __restrict__ out) {
    if (threadIdx.x == 0 && blockIdx.x == 0)
        out[0] = (float)(acc[0] / (double)ncp[0]);
}

extern "C" void kernel_launch(void* const* d_in, const int* in_sizes, int n_in,
                              void* d_out, int out_size, void* d_ws, size_t ws_size,
                              hipStream_t stream) {
    const float* vp    = (const float*)d_in[0];
    const int*   gmap  = (const int*)d_in[1];
    const float* ef    = (const float*)d_in[2];
    const int*   ncp   = (const int*)d_in[3];
    const float* gstep = (const float*)d_in[4];
    const float* epsp  = (const float*)d_in[5];
    float*       out   = (float*)d_out;

    const int n_edges = in_sizes[1] / 2;
    const int* lits = gmap;
    const int* cls  = gmap + n_edges;

    // choose pass count so payload fits the workspace (P=1 needs ~50.3MB)
    int P = 8;
    int nbp_max = (NB_TOTAL + 7) / 8;
    size_t cursors_off_w = (size_t)nbp_max * CAP;
    size_t acc_off_w = (cursors_off_w + NB_TOTAL + 1) & ~(size_t)1;
    const int cands[4] = {1, 2, 4, 8};
    for (int ci = 0; ci < 4; ++ci) {
        int cand = cands[ci];
        int nm = (NB_TOTAL + cand - 1) / cand;
        size_t pw = (size_t)nm * CAP;
        size_t cw = pw + NB_TOTAL;
        size_t aw = (cw + 1) & ~(size_t)1;
        size_t need = aw * 4 + 8;
        if (need <= ws_size) { P = cand; nbp_max = nm; cursors_off_w = pw; acc_off_w = aw; break; }
    }

    uint32_t* payload = (uint32_t*)d_ws;
    uint32_t* cursors = payload + cursors_off_w;
    double*   acc     = (double*)((uint32_t*)d_ws + acc_off_w);

    // zero cursors + accumulator every call (ws is poisoned, not re-zeroed)
    hipMemsetAsync(cursors, 0, (acc_off_w - cursors_off_w) * 4 + 8, stream);

    const int sc_blocks = (n_edges + SC_CHUNK - 1) / SC_CHUNK;  // 489 for 12M
    for (int p = 0; p < P; ++p) {
        int b_lo = p * nbp_max;
        int b_hi = min(NB_TOTAL, b_lo + nbp_max);
        if (b_lo >= b_hi) continue;
        int nbp = b_hi - b_lo;
        scatter_kernel<<<sc_blocks, SC_THREADS, 0, stream>>>(
            vp, lits, cls, (const int*)ef, payload, cursors, n_edges, b_lo, b_hi);
        process_kernel<<<nbp, PR_THREADS, 0, stream>>>(
            payload, cursors, gstep, epsp, acc, b_lo, nbp);
    }
    finalize_kernel<<<1, 64, 0, stream>>>(acc, ncp, out);
}